// Round 13
// baseline (404.182 us; speedup 1.0000x reference)
//
#include <hip/hip_runtime.h>
#include <hip/hip_fp16.h>

// ---------------------------------------------------------------------------
// GCN graph classification: 3x GCNConv(128->128) + mean/max pool + FC(256->10)
// Round 13: CSR build widened (CB=512 chunk blocks for hist/bucket) and
//           binscan+s512scan merged via last-block ticket (one fewer
//           dispatch). Pipeline otherwise identical to R12.
// ---------------------------------------------------------------------------

typedef _Float16 f16;
typedef f16 f16x8 __attribute__((ext_vector_type(8)));
typedef f16 f16x4 __attribute__((ext_vector_type(4)));
typedef f16 f16x2 __attribute__((ext_vector_type(2)));
typedef float f32x4 __attribute__((ext_vector_type(4)));

#define BIN_BITS 8
#define BINSZ 256
#define CB 512              // chunk blocks for the two edge-streaming passes
#define SRC_BITS 17         // N < 131072

// --- prep: W frag-pack (24 blocks) + per-chunk bin histogram (CB blocks) ---
__global__ __launch_bounds__(256) void prep_count(const float* __restrict__ W1,
                                                  const float* __restrict__ W2,
                                                  const float* __restrict__ W3,
                                                  f16x8* __restrict__ wf,
                                                  const int* __restrict__ dst,
                                                  int* __restrict__ bcnt,
                                                  int* __restrict__ ticket,
                                                  int ne, int nb, int chunk) {
    int bid = blockIdx.x;
    int t = threadIdx.x;
    if (bid < 24) {
        if (bid == 0 && t == 0) *ticket = 0;   // reset decoupled-scan ticket
        int layer = bid >> 3;
        const float* W = (layer == 0) ? W1 : (layer == 1 ? W2 : W3);
        int tid2 = (bid & 7) * 256 + t;   // 0..2047
        int ch = tid2 >> 10;
        int ct = (tid2 >> 8) & 3;
        int tt = (tid2 >> 6) & 3;
        int l  = tid2 & 63;
        int c  = ch * 64 + ct * 16 + (l & 15);
        int k0 = tt * 32 + ((l >> 4) << 3);
        f16x8 v;
#pragma unroll
        for (int j = 0; j < 8; ++j) v[j] = (f16)W[(size_t)(k0 + j) * 128 + c];
        wf[layer * 2048 + tid2] = v;
        return;
    }
    __shared__ int h[512];
    int b = bid - 24;
    for (int i = t; i < 512; i += 256) h[i] = 0;
    __syncthreads();
    int e0 = b * chunk, e1 = min(ne, e0 + chunk);
    for (int e = e0 + t; e < e1; e += 256)
        atomicAdd(&h[dst[e] >> BIN_BITS], 1);
    __syncthreads();
    for (int i = t; i < nb; i += 256) bcnt[(size_t)b * 512 + i] = h[i];
}

// per-bin exclusive scan over the CB chunk-blocks (512 threads), then the
// LAST block (atomic ticket) performs the final scan of bin totals -> base.
__global__ __launch_bounds__(512) void binscan(int* __restrict__ bcnt,
                                               int* __restrict__ tot,
                                               int* __restrict__ base,
                                               int* __restrict__ row_ptr,
                                               int* __restrict__ ticket,
                                               int nb, int n, int ne) {
    __shared__ int ws[8];
    __shared__ int lastFlag;
    int bin = blockIdx.x;
    int t = threadIdx.x;
    int lane = t & 63, wid = t >> 6;
    {
        int v = bcnt[(size_t)t * 512 + bin];
        int sc = v;
#pragma unroll
        for (int off = 1; off < 64; off <<= 1) {
            int u = __shfl_up(sc, off, 64);
            if (lane >= off) sc += u;
        }
        if (lane == 63) ws[wid] = sc;
        __syncthreads();
        if (t == 0) { int r = 0; for (int i = 0; i < 8; ++i) { int x = ws[i]; ws[i] = r; r += x; } }
        __syncthreads();
        int excl = ws[wid] + sc - v;
        bcnt[(size_t)t * 512 + bin] = excl;
        if (t == 511) tot[bin] = excl + v;
    }
    // decoupled final scan by the last-arriving block
    __threadfence();
    __syncthreads();
    if (t == 0) lastFlag = (atomicAdd(ticket, 1) == gridDim.x - 1) ? 1 : 0;
    __syncthreads();
    if (!lastFlag) return;
    __threadfence();
    int v = (t < nb) ? tot[t] : 0;
    int sc = v;
#pragma unroll
    for (int off = 1; off < 64; off <<= 1) {
        int u = __shfl_up(sc, off, 64);
        if (lane >= off) sc += u;
    }
    if (lane == 63) ws[wid] = sc;
    __syncthreads();
    if (t == 0) { int r = 0; for (int i = 0; i < 8; ++i) { int x = ws[i]; ws[i] = r; r += x; } }
    __syncthreads();
    int excl = ws[wid] + sc - v;
    if (t < nb) base[t] = excl;
    if (t == 0) { base[nb] = ne; row_ptr[n] = ne; }
}

// pass 2: re-stream edges, place packed (src | local<<SRC_BITS) into the
// bin-grouped ebuf at base[bin] + rel[block][bin] + LDS-rank. No global atomics.
__global__ __launch_bounds__(256) void bucket_place(const int* __restrict__ src,
                                                    const int* __restrict__ dst,
                                                    const int* __restrict__ base,
                                                    const int* __restrict__ bcnt,
                                                    unsigned* __restrict__ ebuf,
                                                    int ne, int nb, int chunk) {
    __shared__ int cur[512];
    __shared__ int rel[512];
    int b = blockIdx.x;
    int t = threadIdx.x;
    for (int i = t; i < 512; i += 256) {
        cur[i] = 0;
        rel[i] = (i < nb) ? (base[i] + bcnt[(size_t)b * 512 + i]) : 0;
    }
    __syncthreads();
    int e0 = b * chunk, e1 = min(ne, e0 + chunk);
    for (int e = e0 + t; e < e1; e += 256) {
        int d = dst[e];
        int s = src[e];
        int bin = d >> BIN_BITS;
        int rank = atomicAdd(&cur[bin], 1);
        ebuf[(size_t)rel[bin] + rank] = (unsigned)s | ((unsigned)(d & (BINSZ - 1)) << SRC_BITS);
    }
}

// one block per bin (512 threads): LDS hist -> scan -> row_ptr/dinv ->
// LDS-cursor place (writes confined to the bin's L2-resident window).
__global__ __launch_bounds__(512) void place_kernel(const unsigned* __restrict__ ebuf,
                                                    const int* __restrict__ base,
                                                    int* __restrict__ row_ptr,
                                                    int* __restrict__ csr,
                                                    float* __restrict__ dinv, int n) {
    __shared__ int hist[BINSZ];
    __shared__ int cur[BINSZ];
    __shared__ int ws[4];
    int bin = blockIdx.x;
    int t = threadIdx.x;
    int node0 = bin << BIN_BITS;
    int ebeg = base[bin], eend = base[bin + 1];
    if (t < BINSZ) hist[t] = 0;
    __syncthreads();
    for (int p = ebeg + t; p < eend; p += 512)
        atomicAdd(&hist[ebuf[p] >> SRC_BITS], 1);
    __syncthreads();
    int lane = t & 63, wid = t >> 6;
    int c = 0, sc = 0;
    if (t < 256) {
        c = hist[t];
        sc = c;
#pragma unroll
        for (int off = 1; off < 64; off <<= 1) {
            int u = __shfl_up(sc, off, 64);
            if (lane >= off) sc += u;
        }
        if (lane == 63) ws[wid] = sc;
    }
    __syncthreads();
    if (t == 0) { int r = 0; for (int i = 0; i < 4; ++i) { int x = ws[i]; ws[i] = r; r += x; } }
    __syncthreads();
    if (t < 256) {
        int excl = ws[wid] + sc - c;
        int node = node0 + t;
        if (node < n) {
            row_ptr[node] = ebeg + excl;
            dinv[node] = 1.0f / sqrtf((float)c + 1.0f);
        }
        cur[t] = excl;
    }
    __syncthreads();
    for (int p = ebeg + t; p < eend; p += 512) {
        unsigned v = ebuf[p];
        int local = v >> SRC_BITS;
        int r = atomicAdd(&cur[local], 1);
        csr[ebeg + r] = (int)(v & ((1u << SRC_BITS) - 1));
    }
}

// --- MFMA GEMM core: Y[m,:] = fp16( dinv[m] * (X[m,:] @ W) ) ---------------
template <bool XHALF>
__device__ __forceinline__ void gemm_core(const void* __restrict__ Xv,
                                          const f16x8* __restrict__ wf,
                                          const float* __restrict__ dinv,
                                          f16* __restrict__ Y, int n, int bid) {
    const int tid = threadIdx.x;
    const int l = tid & 63;
    const int w = tid >> 6;
    const int ch = w & 1;
    const int row0 = bid * 64 + (w >> 1) * 32;
    const int m = l & 15;
    const int kg = l >> 4;

    f16x8 bw[4][4];
#pragma unroll
    for (int ct = 0; ct < 4; ++ct)
#pragma unroll
        for (int t = 0; t < 4; ++t)
            bw[ct][t] = wf[((ch * 4 + ct) * 4 + t) * 64 + l];

    f32x4 acc[2][4];
#pragma unroll
    for (int mt = 0; mt < 2; ++mt)
#pragma unroll
        for (int ct = 0; ct < 4; ++ct) acc[mt][ct] = (f32x4){0.f, 0.f, 0.f, 0.f};

    int mrow[2];
#pragma unroll
    for (int mt = 0; mt < 2; ++mt) {
        int r = row0 + mt * 16 + m;
        mrow[mt] = (r < n) ? r : (n - 1);
    }

#pragma unroll
    for (int t = 0; t < 4; ++t) {
        f16x8 xf[2];
#pragma unroll
        for (int mt = 0; mt < 2; ++mt) {
            if constexpr (XHALF) {
                xf[mt] = *(const f16x8*)((const f16*)Xv + (size_t)mrow[mt] * 128 + t * 32 + kg * 8);
            } else {
                const float* Xf = (const float*)Xv + (size_t)mrow[mt] * 128 + t * 32 + kg * 8;
                float4 p = *(const float4*)Xf;
                float4 q = *(const float4*)(Xf + 4);
                f16x8 h;
                h[0] = (f16)p.x; h[1] = (f16)p.y; h[2] = (f16)p.z; h[3] = (f16)p.w;
                h[4] = (f16)q.x; h[5] = (f16)q.y; h[6] = (f16)q.z; h[7] = (f16)q.w;
                xf[mt] = h;
            }
        }
#pragma unroll
        for (int mt = 0; mt < 2; ++mt)
#pragma unroll
            for (int ct = 0; ct < 4; ++ct)
                acc[mt][ct] = __builtin_amdgcn_mfma_f32_16x16x32_f16(
                    bw[ct][t], xf[mt], acc[mt][ct], 0, 0, 0);
    }

#pragma unroll
    for (int mt = 0; mt < 2; ++mt) {
        int row = row0 + mt * 16 + m;
        if (row >= n) continue;
        float dv = dinv[row];
#pragma unroll
        for (int ct = 0; ct < 4; ++ct) {
            f16x4 o;
#pragma unroll
            for (int r = 0; r < 4; ++r) o[r] = (f16)(acc[mt][ct][r] * dv);
            *(f16x4*)&Y[(size_t)row * 128 + ch * 64 + ct * 16 + kg * 4] = o;
        }
    }
}

__global__ __launch_bounds__(256) void gemm_mfma_h(const f16* __restrict__ X,
                                                   const f16x8* __restrict__ wf,
                                                   const float* __restrict__ dinv,
                                                   f16* __restrict__ Y, int n) {
    gemm_core<true>(X, wf, dinv, Y, n, blockIdx.x);
}

__global__ __launch_bounds__(256) void gemm_mfma_f(const float* __restrict__ X,
                                                   const f16x8* __restrict__ wf,
                                                   const float* __restrict__ dinv,
                                                   f16* __restrict__ Y, int n) {
    gemm_core<false>(X, wf, dinv, Y, n, blockIdx.x);
}

// A[d,:] = fp16( relu( dinv[d]*(sum_{e in row d} Y[src,:] + Y[d,:]) + b ) )
// Y pre-scaled by dinv. 64 lanes/node (f16x2 each), 8-deep clamp-padded
// scalarized gather, pure unweighted adds.
__global__ __launch_bounds__(256) void agg_fused(const f16* __restrict__ Y,
                                                 const int* __restrict__ row_ptr,
                                                 const int* __restrict__ csr,
                                                 const float* __restrict__ dinv,
                                                 const float* __restrict__ b,
                                                 f16* __restrict__ A, int n) {
    int node = (int)((blockIdx.x * 256 + threadIdx.x) >> 6);
    node = __builtin_amdgcn_readfirstlane(node);
    if (node >= n) return;
    int lane = threadIdx.x & 63;
    const f16x2* Yv = (const f16x2*)Y;
    size_t rowOff = (size_t)node * 64;
    f16x2 sv = Yv[rowOff + lane];           // self loop
    float ax = (float)sv[0], ay = (float)sv[1];
    int beg = row_ptr[node], end = row_ptr[node + 1];
    for (int e = beg; e < end; e += 8) {
        int idx[8];
        float w[8];
#pragma unroll
        for (int u = 0; u < 8; ++u) {
            int ee = e + u;
            bool live = ee < end;
            int cl = live ? ee : end - 1;
            int s = csr[cl];
            idx[u] = __builtin_amdgcn_readfirstlane(live ? s : node);
            w[u] = live ? 1.f : 0.f;
        }
#pragma unroll
        for (int u = 0; u < 8; ++u) {
            f16x2 v = Yv[(size_t)idx[u] * 64 + lane];
            ax = fmaf(w[u], (float)v[0], ax);
            ay = fmaf(w[u], (float)v[1], ay);
        }
    }
    float dn = dinv[node];
    float2 bb = *(const float2*)&b[2 * lane];
    f16x2 o;
    o[0] = (f16)fmaxf(fmaf(ax, dn, bb.x), 0.f);
    o[1] = (f16)fmaxf(fmaf(ay, dn, bb.y), 0.f);
    *((f16x2*)A + rowOff + lane) = o;
}

__device__ __forceinline__ int lower_bound(const int* __restrict__ a, int n, int key) {
    int lo = 0, hi = n;
    while (lo < hi) {
        int mid = (lo + hi) >> 1;
        if (a[mid] < key) lo = mid + 1; else hi = mid;
    }
    return lo;
}

// block per graph: pool (4 node-parallel groups x 64 lanes x f16x2) + FC.
__global__ __launch_bounds__(256) void poolfc_kernel(const f16* __restrict__ H,
                                                     const int* __restrict__ batch,
                                                     const float* __restrict__ fcW,
                                                     const float* __restrict__ fcb,
                                                     float* __restrict__ out,
                                                     int n, int C) {
    __shared__ float red[3][64][4];
    __shared__ float p[256];
    int g = blockIdx.x;
    int beg = lower_bound(batch, n, g);
    int end = lower_bound(batch, n, g + 1);
    int t = threadIdx.x, sub = t >> 6, lane = t & 63;
    const f16x2* Hv = (const f16x2*)H;
    float sx = 0.f, sy = 0.f, mx = -INFINITY, my = -INFINITY;
    for (int i = beg + sub; i < end; i += 4) {
        f16x2 v = Hv[(size_t)i * 64 + lane];
        float a = (float)v[0], c = (float)v[1];
        sx += a; sy += c;
        mx = fmaxf(mx, a); my = fmaxf(my, c);
    }
    if (sub) {
        red[sub - 1][lane][0] = sx; red[sub - 1][lane][1] = sy;
        red[sub - 1][lane][2] = mx; red[sub - 1][lane][3] = my;
    }
    __syncthreads();
    if (sub == 0) {
#pragma unroll
        for (int k = 0; k < 3; ++k) {
            sx += red[k][lane][0]; sy += red[k][lane][1];
            mx = fmaxf(mx, red[k][lane][2]); my = fmaxf(my, red[k][lane][3]);
        }
        float cnt = fmaxf((float)(end - beg), 1.0f);
        p[2 * lane]           = sx / cnt;
        p[2 * lane + 1]       = sy / cnt;
        p[128 + 2 * lane]     = mx;
        p[128 + 2 * lane + 1] = my;
    }
    __syncthreads();
    if (t < C) {
        float acc = fcb[t];
        for (int k = 0; k < 256; ++k) acc = fmaf(p[k], fcW[k * C + t], acc);
        out[(size_t)g * C + t] = acc;
    }
}

extern "C" void kernel_launch(void* const* d_in, const int* in_sizes, int n_in,
                              void* d_out, int out_size, void* d_ws, size_t ws_size,
                              hipStream_t stream) {
    const float* x     = (const float*)d_in[0];
    const int*   ei    = (const int*)d_in[1];
    const int*   batch = (const int*)d_in[2];
    const float* W1    = (const float*)d_in[3];
    const float* b1    = (const float*)d_in[4];
    const float* W2    = (const float*)d_in[5];
    const float* b2    = (const float*)d_in[6];
    const float* W3    = (const float*)d_in[7];
    const float* b3    = (const float*)d_in[8];
    const float* fcW   = (const float*)d_in[9];
    const float* fcb   = (const float*)d_in[10];

    const int N = in_sizes[0] / 128;
    const int E = in_sizes[1] / 2;
    const int C = in_sizes[10];
    const int G = out_size / C;
    const int NB = (N + BINSZ - 1) >> BIN_BITS;       // <= 512
    const int chunk = (E + CB - 1) / CB;
    float* out = (float*)d_out;

    // workspace layout
    f16*      Yh      = (f16*)d_ws;                          // [N*128]
    f16*      Ah      = Yh + (size_t)N * 128;                // [N*128]
    f16x8*    wf      = (f16x8*)(Ah + (size_t)N * 128);      // [3*2048]
    float*    dinv    = (float*)(wf + 3 * 2048);             // [N]
    int*      row_ptr = (int*)(dinv + N);                    // [N+8]
    int*      csr_src = row_ptr + N + 8;                     // [E]
    unsigned* ebuf    = (unsigned*)(csr_src + E);            // [E]
    int*      bcnt    = (int*)(ebuf + E);                    // [CB*512]
    int*      tot     = bcnt + (size_t)CB * 512;             // [512]
    int*      base    = tot + 512;                           // [512+8]
    int*      ticket  = base + 512 + 8;                      // [1]

    const int* src = ei;
    const int* dst = ei + E;

    const int gemmBlocks = (N + 63) / 64;
    const int aggBlocks = (int)(((long long)N * 64 + 255) / 256);

    // --- deterministic radix CSR build (no global cursor atomics) ---
    prep_count<<<24 + CB, 256, 0, stream>>>(W1, W2, W3, wf, dst, bcnt, ticket, E, NB, chunk);
    binscan<<<NB, 512, 0, stream>>>(bcnt, tot, base, row_ptr, ticket, NB, N, E);
    bucket_place<<<CB, 256, 0, stream>>>(src, dst, base, bcnt, ebuf, E, NB, chunk);
    place_kernel<<<NB, 512, 0, stream>>>(ebuf, base, row_ptr, csr_src, dinv, N);

    // layers (all scaled: dinv folded into each GEMM epilogue)
    gemm_mfma_f<<<gemmBlocks, 256, 0, stream>>>(x, wf, dinv, Yh, N);
    agg_fused<<<aggBlocks, 256, 0, stream>>>(Yh, row_ptr, csr_src, dinv, b1, Ah, N);
    gemm_mfma_h<<<gemmBlocks, 256, 0, stream>>>(Ah, wf + 2048, dinv, Yh, N);
    agg_fused<<<aggBlocks, 256, 0, stream>>>(Yh, row_ptr, csr_src, dinv, b2, Ah, N);
    gemm_mfma_h<<<gemmBlocks, 256, 0, stream>>>(Ah, wf + 4096, dinv, Yh, N);
    agg_fused<<<aggBlocks, 256, 0, stream>>>(Yh, row_ptr, csr_src, dinv, b3, Ah, N);

    poolfc_kernel<<<G, 256, 0, stream>>>(Ah, batch, fcW, fcb, out, N, C);
}

// Round 14
// 317.660 us; speedup vs baseline: 1.2724x; 1.2724x over previous
//
#include <hip/hip_runtime.h>
#include <hip/hip_fp16.h>

// ---------------------------------------------------------------------------
// GCN graph classification: 3x GCNConv(128->128) + mean/max pool + FC(256->10)
// Round 14: exact revert to R12 (best verified: 317.7 us). R13's ticket-fence
//           merge and CB=512 both regressed (agent-scope fence = L2 flush per
//           block; wider bcnt = more uncoalesced column reads).
// ---------------------------------------------------------------------------

typedef _Float16 f16;
typedef f16 f16x8 __attribute__((ext_vector_type(8)));
typedef f16 f16x4 __attribute__((ext_vector_type(4)));
typedef f16 f16x2 __attribute__((ext_vector_type(2)));
typedef float f32x4 __attribute__((ext_vector_type(4)));

#define BIN_BITS 8
#define BINSZ 256
#define CB 256              // chunk blocks for bucket passes
#define SRC_BITS 17         // N < 131072

// --- prep: W frag-pack (24 blocks) + per-chunk bin histogram (CB blocks) ---
__global__ __launch_bounds__(256) void prep_count(const float* __restrict__ W1,
                                                  const float* __restrict__ W2,
                                                  const float* __restrict__ W3,
                                                  f16x8* __restrict__ wf,
                                                  const int* __restrict__ dst,
                                                  int* __restrict__ bcnt,
                                                  int ne, int nb, int chunk) {
    int bid = blockIdx.x;
    int t = threadIdx.x;
    if (bid < 24) {
        int layer = bid >> 3;
        const float* W = (layer == 0) ? W1 : (layer == 1 ? W2 : W3);
        int tid2 = (bid & 7) * 256 + t;   // 0..2047
        int ch = tid2 >> 10;
        int ct = (tid2 >> 8) & 3;
        int tt = (tid2 >> 6) & 3;
        int l  = tid2 & 63;
        int c  = ch * 64 + ct * 16 + (l & 15);
        int k0 = tt * 32 + ((l >> 4) << 3);
        f16x8 v;
#pragma unroll
        for (int j = 0; j < 8; ++j) v[j] = (f16)W[(size_t)(k0 + j) * 128 + c];
        wf[layer * 2048 + tid2] = v;
        return;
    }
    __shared__ int h[512];
    int b = bid - 24;
    for (int i = t; i < 512; i += 256) h[i] = 0;
    __syncthreads();
    int e0 = b * chunk, e1 = min(ne, e0 + chunk);
    for (int e = e0 + t; e < e1; e += 256)
        atomicAdd(&h[dst[e] >> BIN_BITS], 1);
    __syncthreads();
    for (int i = t; i < nb; i += 256) bcnt[(size_t)b * 512 + i] = h[i];
}

// per-bin exclusive scan over the CB chunk-blocks; rel written in place.
__global__ __launch_bounds__(256) void binscan(int* __restrict__ bcnt,
                                               int* __restrict__ tot, int nb) {
    __shared__ int ws[4];
    int bin = blockIdx.x;
    int t = threadIdx.x;
    int v = bcnt[(size_t)t * 512 + bin];
    int lane = t & 63, wid = t >> 6;
    int sc = v;
#pragma unroll
    for (int off = 1; off < 64; off <<= 1) {
        int u = __shfl_up(sc, off, 64);
        if (lane >= off) sc += u;
    }
    if (lane == 63) ws[wid] = sc;
    __syncthreads();
    if (t == 0) { int r = 0; for (int i = 0; i < 4; ++i) { int x = ws[i]; ws[i] = r; r += x; } }
    __syncthreads();
    int excl = ws[wid] + sc - v;
    bcnt[(size_t)t * 512 + bin] = excl;
    if (t == 255) tot[bin] = excl + v;
}

// exclusive scan of <=512 bin totals -> base[]; also base[nb]=ne, row_ptr[n]=ne
__global__ __launch_bounds__(512) void s512scan(const int* __restrict__ tot,
                                                int* __restrict__ base,
                                                int* __restrict__ row_ptr,
                                                int nb, int n, int ne) {
    __shared__ int ws[8];
    int t = threadIdx.x;
    int v = (t < nb) ? tot[t] : 0;
    int lane = t & 63, wid = t >> 6;
    int sc = v;
#pragma unroll
    for (int off = 1; off < 64; off <<= 1) {
        int u = __shfl_up(sc, off, 64);
        if (lane >= off) sc += u;
    }
    if (lane == 63) ws[wid] = sc;
    __syncthreads();
    if (t == 0) { int r = 0; for (int i = 0; i < 8; ++i) { int x = ws[i]; ws[i] = r; r += x; } }
    __syncthreads();
    int excl = ws[wid] + sc - v;
    if (t < nb) base[t] = excl;
    if (t == 0) { base[nb] = ne; row_ptr[n] = ne; }
}

// pass 2: re-stream edges, place packed (src | local<<SRC_BITS) into the
// bin-grouped ebuf at base[bin] + rel[block][bin] + LDS-rank. No global atomics.
__global__ __launch_bounds__(256) void bucket_place(const int* __restrict__ src,
                                                    const int* __restrict__ dst,
                                                    const int* __restrict__ base,
                                                    const int* __restrict__ bcnt,
                                                    unsigned* __restrict__ ebuf,
                                                    int ne, int nb, int chunk) {
    __shared__ int cur[512];
    __shared__ int rel[512];
    int b = blockIdx.x;
    int t = threadIdx.x;
    for (int i = t; i < 512; i += 256) {
        cur[i] = 0;
        rel[i] = (i < nb) ? (base[i] + bcnt[(size_t)b * 512 + i]) : 0;
    }
    __syncthreads();
    int e0 = b * chunk, e1 = min(ne, e0 + chunk);
    for (int e = e0 + t; e < e1; e += 256) {
        int d = dst[e];
        int s = src[e];
        int bin = d >> BIN_BITS;
        int rank = atomicAdd(&cur[bin], 1);
        ebuf[(size_t)rel[bin] + rank] = (unsigned)s | ((unsigned)(d & (BINSZ - 1)) << SRC_BITS);
    }
}

// one block per bin (512 threads): LDS hist -> scan -> row_ptr/dinv ->
// LDS-cursor place (writes confined to the bin's L2-resident window).
__global__ __launch_bounds__(512) void place_kernel(const unsigned* __restrict__ ebuf,
                                                    const int* __restrict__ base,
                                                    int* __restrict__ row_ptr,
                                                    int* __restrict__ csr,
                                                    float* __restrict__ dinv, int n) {
    __shared__ int hist[BINSZ];
    __shared__ int cur[BINSZ];
    __shared__ int ws[4];
    int bin = blockIdx.x;
    int t = threadIdx.x;
    int node0 = bin << BIN_BITS;
    int ebeg = base[bin], eend = base[bin + 1];
    if (t < BINSZ) hist[t] = 0;
    __syncthreads();
    for (int p = ebeg + t; p < eend; p += 512)
        atomicAdd(&hist[ebuf[p] >> SRC_BITS], 1);
    __syncthreads();
    int lane = t & 63, wid = t >> 6;
    int c = 0, sc = 0;
    if (t < 256) {
        c = hist[t];
        sc = c;
#pragma unroll
        for (int off = 1; off < 64; off <<= 1) {
            int u = __shfl_up(sc, off, 64);
            if (lane >= off) sc += u;
        }
        if (lane == 63) ws[wid] = sc;
    }
    __syncthreads();
    if (t == 0) { int r = 0; for (int i = 0; i < 4; ++i) { int x = ws[i]; ws[i] = r; r += x; } }
    __syncthreads();
    if (t < 256) {
        int excl = ws[wid] + sc - c;
        int node = node0 + t;
        if (node < n) {
            row_ptr[node] = ebeg + excl;
            dinv[node] = 1.0f / sqrtf((float)c + 1.0f);
        }
        cur[t] = excl;
    }
    __syncthreads();
    for (int p = ebeg + t; p < eend; p += 512) {
        unsigned v = ebuf[p];
        int local = v >> SRC_BITS;
        int r = atomicAdd(&cur[local], 1);
        csr[ebeg + r] = (int)(v & ((1u << SRC_BITS) - 1));
    }
}

// --- MFMA GEMM core: Y[m,:] = fp16( dinv[m] * (X[m,:] @ W) ) ---------------
template <bool XHALF>
__device__ __forceinline__ void gemm_core(const void* __restrict__ Xv,
                                          const f16x8* __restrict__ wf,
                                          const float* __restrict__ dinv,
                                          f16* __restrict__ Y, int n, int bid) {
    const int tid = threadIdx.x;
    const int l = tid & 63;
    const int w = tid >> 6;
    const int ch = w & 1;
    const int row0 = bid * 64 + (w >> 1) * 32;
    const int m = l & 15;
    const int kg = l >> 4;

    f16x8 bw[4][4];
#pragma unroll
    for (int ct = 0; ct < 4; ++ct)
#pragma unroll
        for (int t = 0; t < 4; ++t)
            bw[ct][t] = wf[((ch * 4 + ct) * 4 + t) * 64 + l];

    f32x4 acc[2][4];
#pragma unroll
    for (int mt = 0; mt < 2; ++mt)
#pragma unroll
        for (int ct = 0; ct < 4; ++ct) acc[mt][ct] = (f32x4){0.f, 0.f, 0.f, 0.f};

    int mrow[2];
#pragma unroll
    for (int mt = 0; mt < 2; ++mt) {
        int r = row0 + mt * 16 + m;
        mrow[mt] = (r < n) ? r : (n - 1);
    }

#pragma unroll
    for (int t = 0; t < 4; ++t) {
        f16x8 xf[2];
#pragma unroll
        for (int mt = 0; mt < 2; ++mt) {
            if constexpr (XHALF) {
                xf[mt] = *(const f16x8*)((const f16*)Xv + (size_t)mrow[mt] * 128 + t * 32 + kg * 8);
            } else {
                const float* Xf = (const float*)Xv + (size_t)mrow[mt] * 128 + t * 32 + kg * 8;
                float4 p = *(const float4*)Xf;
                float4 q = *(const float4*)(Xf + 4);
                f16x8 h;
                h[0] = (f16)p.x; h[1] = (f16)p.y; h[2] = (f16)p.z; h[3] = (f16)p.w;
                h[4] = (f16)q.x; h[5] = (f16)q.y; h[6] = (f16)q.z; h[7] = (f16)q.w;
                xf[mt] = h;
            }
        }
#pragma unroll
        for (int mt = 0; mt < 2; ++mt)
#pragma unroll
            for (int ct = 0; ct < 4; ++ct)
                acc[mt][ct] = __builtin_amdgcn_mfma_f32_16x16x32_f16(
                    bw[ct][t], xf[mt], acc[mt][ct], 0, 0, 0);
    }

#pragma unroll
    for (int mt = 0; mt < 2; ++mt) {
        int row = row0 + mt * 16 + m;
        if (row >= n) continue;
        float dv = dinv[row];
#pragma unroll
        for (int ct = 0; ct < 4; ++ct) {
            f16x4 o;
#pragma unroll
            for (int r = 0; r < 4; ++r) o[r] = (f16)(acc[mt][ct][r] * dv);
            *(f16x4*)&Y[(size_t)row * 128 + ch * 64 + ct * 16 + kg * 4] = o;
        }
    }
}

__global__ __launch_bounds__(256) void gemm_mfma_h(const f16* __restrict__ X,
                                                   const f16x8* __restrict__ wf,
                                                   const float* __restrict__ dinv,
                                                   f16* __restrict__ Y, int n) {
    gemm_core<true>(X, wf, dinv, Y, n, blockIdx.x);
}

__global__ __launch_bounds__(256) void gemm_mfma_f(const float* __restrict__ X,
                                                   const f16x8* __restrict__ wf,
                                                   const float* __restrict__ dinv,
                                                   f16* __restrict__ Y, int n) {
    gemm_core<false>(X, wf, dinv, Y, n, blockIdx.x);
}

// A[d,:] = fp16( relu( dinv[d]*(sum_{e in row d} Y[src,:] + Y[d,:]) + b ) )
// Y pre-scaled by dinv. 64 lanes/node (f16x2 each), 8-deep clamp-padded
// scalarized gather, pure unweighted adds.
__global__ __launch_bounds__(256) void agg_fused(const f16* __restrict__ Y,
                                                 const int* __restrict__ row_ptr,
                                                 const int* __restrict__ csr,
                                                 const float* __restrict__ dinv,
                                                 const float* __restrict__ b,
                                                 f16* __restrict__ A, int n) {
    int node = (int)((blockIdx.x * 256 + threadIdx.x) >> 6);
    node = __builtin_amdgcn_readfirstlane(node);
    if (node >= n) return;
    int lane = threadIdx.x & 63;
    const f16x2* Yv = (const f16x2*)Y;
    size_t rowOff = (size_t)node * 64;
    f16x2 sv = Yv[rowOff + lane];           // self loop
    float ax = (float)sv[0], ay = (float)sv[1];
    int beg = row_ptr[node], end = row_ptr[node + 1];
    for (int e = beg; e < end; e += 8) {
        int idx[8];
        float w[8];
#pragma unroll
        for (int u = 0; u < 8; ++u) {
            int ee = e + u;
            bool live = ee < end;
            int cl = live ? ee : end - 1;
            int s = csr[cl];
            idx[u] = __builtin_amdgcn_readfirstlane(live ? s : node);
            w[u] = live ? 1.f : 0.f;
        }
#pragma unroll
        for (int u = 0; u < 8; ++u) {
            f16x2 v = Yv[(size_t)idx[u] * 64 + lane];
            ax = fmaf(w[u], (float)v[0], ax);
            ay = fmaf(w[u], (float)v[1], ay);
        }
    }
    float dn = dinv[node];
    float2 bb = *(const float2*)&b[2 * lane];
    f16x2 o;
    o[0] = (f16)fmaxf(fmaf(ax, dn, bb.x), 0.f);
    o[1] = (f16)fmaxf(fmaf(ay, dn, bb.y), 0.f);
    *((f16x2*)A + rowOff + lane) = o;
}

__device__ __forceinline__ int lower_bound(const int* __restrict__ a, int n, int key) {
    int lo = 0, hi = n;
    while (lo < hi) {
        int mid = (lo + hi) >> 1;
        if (a[mid] < key) lo = mid + 1; else hi = mid;
    }
    return lo;
}

// block per graph: pool (4 node-parallel groups x 64 lanes x f16x2) + FC.
__global__ __launch_bounds__(256) void poolfc_kernel(const f16* __restrict__ H,
                                                     const int* __restrict__ batch,
                                                     const float* __restrict__ fcW,
                                                     const float* __restrict__ fcb,
                                                     float* __restrict__ out,
                                                     int n, int C) {
    __shared__ float red[3][64][4];
    __shared__ float p[256];
    int g = blockIdx.x;
    int beg = lower_bound(batch, n, g);
    int end = lower_bound(batch, n, g + 1);
    int t = threadIdx.x, sub = t >> 6, lane = t & 63;
    const f16x2* Hv = (const f16x2*)H;
    float sx = 0.f, sy = 0.f, mx = -INFINITY, my = -INFINITY;
    for (int i = beg + sub; i < end; i += 4) {
        f16x2 v = Hv[(size_t)i * 64 + lane];
        float a = (float)v[0], c = (float)v[1];
        sx += a; sy += c;
        mx = fmaxf(mx, a); my = fmaxf(my, c);
    }
    if (sub) {
        red[sub - 1][lane][0] = sx; red[sub - 1][lane][1] = sy;
        red[sub - 1][lane][2] = mx; red[sub - 1][lane][3] = my;
    }
    __syncthreads();
    if (sub == 0) {
#pragma unroll
        for (int k = 0; k < 3; ++k) {
            sx += red[k][lane][0]; sy += red[k][lane][1];
            mx = fmaxf(mx, red[k][lane][2]); my = fmaxf(my, red[k][lane][3]);
        }
        float cnt = fmaxf((float)(end - beg), 1.0f);
        p[2 * lane]           = sx / cnt;
        p[2 * lane + 1]       = sy / cnt;
        p[128 + 2 * lane]     = mx;
        p[128 + 2 * lane + 1] = my;
    }
    __syncthreads();
    if (t < C) {
        float acc = fcb[t];
        for (int k = 0; k < 256; ++k) acc = fmaf(p[k], fcW[k * C + t], acc);
        out[(size_t)g * C + t] = acc;
    }
}

extern "C" void kernel_launch(void* const* d_in, const int* in_sizes, int n_in,
                              void* d_out, int out_size, void* d_ws, size_t ws_size,
                              hipStream_t stream) {
    const float* x     = (const float*)d_in[0];
    const int*   ei    = (const int*)d_in[1];
    const int*   batch = (const int*)d_in[2];
    const float* W1    = (const float*)d_in[3];
    const float* b1    = (const float*)d_in[4];
    const float* W2    = (const float*)d_in[5];
    const float* b2    = (const float*)d_in[6];
    const float* W3    = (const float*)d_in[7];
    const float* b3    = (const float*)d_in[8];
    const float* fcW   = (const float*)d_in[9];
    const float* fcb   = (const float*)d_in[10];

    const int N = in_sizes[0] / 128;
    const int E = in_sizes[1] / 2;
    const int C = in_sizes[10];
    const int G = out_size / C;
    const int NB = (N + BINSZ - 1) >> BIN_BITS;       // <= 512
    const int chunk = (E + CB - 1) / CB;
    float* out = (float*)d_out;

    // workspace layout
    f16*      Yh      = (f16*)d_ws;                          // [N*128]
    f16*      Ah      = Yh + (size_t)N * 128;                // [N*128]
    f16x8*    wf      = (f16x8*)(Ah + (size_t)N * 128);      // [3*2048]
    float*    dinv    = (float*)(wf + 3 * 2048);             // [N]
    int*      row_ptr = (int*)(dinv + N);                    // [N+8]
    int*      csr_src = row_ptr + N + 8;                     // [E]
    unsigned* ebuf    = (unsigned*)(csr_src + E);            // [E]
    int*      bcnt    = (int*)(ebuf + E);                    // [256*512]
    int*      tot     = bcnt + 256 * 512;                    // [512]
    int*      base    = tot + 512;                           // [512+8]

    const int* src = ei;
    const int* dst = ei + E;

    const int gemmBlocks = (N + 63) / 64;
    const int aggBlocks = (int)(((long long)N * 64 + 255) / 256);

    // --- deterministic radix CSR build (no global atomics) ---
    prep_count<<<24 + CB, 256, 0, stream>>>(W1, W2, W3, wf, dst, bcnt, E, NB, chunk);
    binscan<<<NB, 256, 0, stream>>>(bcnt, tot, NB);
    s512scan<<<1, 512, 0, stream>>>(tot, base, row_ptr, NB, N, E);
    bucket_place<<<CB, 256, 0, stream>>>(src, dst, base, bcnt, ebuf, E, NB, chunk);
    place_kernel<<<NB, 512, 0, stream>>>(ebuf, base, row_ptr, csr_src, dinv, N);

    // layers (all scaled: dinv folded into each GEMM epilogue)
    gemm_mfma_f<<<gemmBlocks, 256, 0, stream>>>(x, wf, dinv, Yh, N);
    agg_fused<<<aggBlocks, 256, 0, stream>>>(Yh, row_ptr, csr_src, dinv, b1, Ah, N);
    gemm_mfma_h<<<gemmBlocks, 256, 0, stream>>>(Ah, wf + 2048, dinv, Yh, N);
    agg_fused<<<aggBlocks, 256, 0, stream>>>(Yh, row_ptr, csr_src, dinv, b2, Ah, N);
    gemm_mfma_h<<<gemmBlocks, 256, 0, stream>>>(Ah, wf + 4096, dinv, Yh, N);
    agg_fused<<<aggBlocks, 256, 0, stream>>>(Yh, row_ptr, csr_src, dinv, b3, Ah, N);

    poolfc_kernel<<<G, 256, 0, stream>>>(Ah, batch, fcW, fcb, out, N, C);
}